// Round 8
// baseline (224.687 us; speedup 1.0000x reference)
//
#include <hip/hip_runtime.h>
#include <hip/hip_bf16.h>

typedef __hip_bfloat16 bf16;
typedef unsigned int u32;
typedef unsigned short u16;
typedef __attribute__((ext_vector_type(8))) short bf16x8;
typedef __attribute__((ext_vector_type(4))) float f32x4;

constexpr int N   = 50000;
constexpr int E   = 1600000;
constexpr int C   = 128;             // channels (H * 32)
constexpr int H   = 4;               // heads
constexpr int NB  = 782;             // dst buckets of 64 nodes (782*64 >= 50000)
constexpr int CAP = 2560;            // LDS staging capacity per bucket in kfill2
constexpr int NCH = 256;             // chunks (bin-count blocks)
constexpr int CHUNK = E / NCH;       // 6250 edges per chunk (exact)
constexpr int GEMM_BLOCKS = 782;     // 782*64 >= 50000 nodes
constexpr float NEG  = 0.2f;
constexpr float SEPS = 1e-16f;
constexpr float LEPS = 1e-5f;

__device__ __forceinline__ float lo16(u32 v) { return __uint_as_float(v << 16); }
__device__ __forceinline__ float hi16(u32 v) { return __uint_as_float(v & 0xFFFF0000u); }
__device__ __forceinline__ u16 bfbits(float f) {
    __hip_bfloat16 h = __float2bfloat16(f);
    return *reinterpret_cast<u16*>(&h);
}

// K0: W f32[k][c] (128x128) -> wt hi/lo bf16[c][k] (split precision).
// R4-validated. 64 KB output stays L2-hot for f1's B-fragment loads.
__global__ __launch_bounds__(256) void k0_wprep(
    const float* __restrict__ W, u16* __restrict__ wt_hi, u16* __restrict__ wt_lo)
{
    const int i = blockIdx.x * 256 + threadIdx.x;   // 64 blocks x 256 = 16384
    const int c = i >> 7, k = i & 127;
    const float w = W[k * 128 + c];
    const __hip_bfloat16 h = __float2bfloat16(w);
    const float fh = __bfloat162float(h);
    wt_hi[i] = *(const u16*)&h;
    wt_lo[i] = bfbits(w - fh);
}

// F1 v2: fused front-end.
//   blocks [0,782): MFMA GEMM. NO LDS: each wave loads its own 16 x-rows'
//     A-fragments straight from global (f32 dwordx4, full cache lines,
//     x has zero inter-wave reuse) and converts to bf16 hi/lo in registers.
//     B-fragments are 16B bf16x8 loads from L2-hot precomputed wt_hi/wt_lo.
//   blocks [782,1038): per-chunk dst-bucket counts -> gcnt[b][c].
__global__ __launch_bounds__(256) void f1_gemm_count(
    const float* __restrict__ x,
    const u16* __restrict__ wt_hi, const u16* __restrict__ wt_lo,
    const float* __restrict__ att_s, const float* __restrict__ att_d,
    const int* __restrict__ ei,
    u16* __restrict__ hb, float* __restrict__ as_, float* __restrict__ ad_,
    u32* __restrict__ gcnt)
{
    __shared__ u32 lcnt[NB];                  // count branch only (~3.1 KB)
    const int t = threadIdx.x;

    if (blockIdx.x >= GEMM_BLOCKS) {
        // ---- bin count branch ----
        const int c = blockIdx.x - GEMM_BLOCKS;
        const int base = c * CHUNK;
        for (int i = t; i < NB; i += 256) lcnt[i] = 0;
        __syncthreads();
        for (int i = t; i < CHUNK; i += 256)
            atomicAdd(&lcnt[((u32)ei[E + base + i]) >> 6], 1u);
        __syncthreads();
        for (int i = t; i < NB; i += 256) gcnt[i * NCH + c] = lcnt[i];
        return;
    }

    // ---- GEMM branch ----
    const int m0   = blockIdx.x * 64;
    const int lane = t & 63;
    const int w    = t >> 6;                  // wave id: rows [w*16, w*16+16)
    const int bcol = lane & 15;               // A row within slice / B col / C col
    const int akg  = lane >> 4;               // k-group 0..3 (8 elems) / C row quarter
    const int aq   = akg;

    // A fragments direct from global: row m0+w*16+bcol, cols ks*32+akg*8 (+8)
    const int arow = min(m0 + w * 16 + bcol, N - 1);
    const float* xr = x + (size_t)arow * 128;
    bf16x8 Ah[4], Al[4];
#pragma unroll
    for (int ks = 0; ks < 4; ++ks) {
        const float4 q0 = *(const float4*)(xr + ks * 32 + akg * 8);
        const float4 q1 = *(const float4*)(xr + ks * 32 + akg * 8 + 4);
        const float f[8] = {q0.x, q0.y, q0.z, q0.w, q1.x, q1.y, q1.z, q1.w};
#pragma unroll
        for (int j = 0; j < 8; ++j) {
            const __hip_bfloat16 hh = __float2bfloat16(f[j]);
            Ah[ks][j] = *(const short*)&hh;
            const __hip_bfloat16 hl = __float2bfloat16(f[j] - __bfloat162float(hh));
            Al[ks][j] = *(const short*)&hl;
        }
    }

    f32x4 acc[8];
#pragma unroll
    for (int nt = 0; nt < 8; ++nt) acc[nt] = f32x4{0.f, 0.f, 0.f, 0.f};

#pragma unroll
    for (int nt = 0; nt < 8; ++nt) {
        const u16* bp = wt_hi + (nt * 16 + bcol) * 128 + akg * 8;
        const u16* bq = wt_lo + (nt * 16 + bcol) * 128 + akg * 8;
#pragma unroll
        for (int ks = 0; ks < 4; ++ks) {
            const bf16x8 Bh = *(const bf16x8*)(bp + ks * 32);
            const bf16x8 Bl = *(const bf16x8*)(bq + ks * 32);
            acc[nt] = __builtin_amdgcn_mfma_f32_16x16x32_bf16(Ah[ks], Bh, acc[nt], 0, 0, 0);
            acc[nt] = __builtin_amdgcn_mfma_f32_16x16x32_bf16(Al[ks], Bh, acc[nt], 0, 0, 0);
            acc[nt] = __builtin_amdgcn_mfma_f32_16x16x32_bf16(Ah[ks], Bl, acc[nt], 0, 0, 0);
        }
    }

    // hb store: C/D layout col=lane&15, row=(lane>>4)*4+reg  [m89/m91]
#pragma unroll
    for (int nt = 0; nt < 8; ++nt) {
        const int ch = nt * 16 + bcol;
#pragma unroll
        for (int r = 0; r < 4; ++r) {
            const int node = m0 + w * 16 + aq * 4 + r;
            if (node < N) hb[(size_t)node * 128 + ch] = bfbits(acc[nt][r]);
        }
    }

    // fused attention dots: per (node, head) sum over the head's 32 channels
    float ps[4][4], pd[4][4];                 // [head][r]
#pragma unroll
    for (int h = 0; h < 4; ++h) {
        const float a0 = att_s[32 * h + bcol], a1 = att_s[32 * h + 16 + bcol];
        const float d0 = att_d[32 * h + bcol], d1 = att_d[32 * h + 16 + bcol];
#pragma unroll
        for (int r = 0; r < 4; ++r) {
            ps[h][r] = acc[2 * h][r] * a0 + acc[2 * h + 1][r] * a1;
            pd[h][r] = acc[2 * h][r] * d0 + acc[2 * h + 1][r] * d1;
        }
    }
#pragma unroll
    for (int off = 1; off < 16; off <<= 1) {
#pragma unroll
        for (int h = 0; h < 4; ++h)
#pragma unroll
            for (int r = 0; r < 4; ++r) {
                ps[h][r] += __shfl_xor(ps[h][r], off, 64);
                pd[h][r] += __shfl_xor(pd[h][r], off, 64);
            }
    }
    if (bcol == 0) {
#pragma unroll
        for (int r = 0; r < 4; ++r) {
            const int node = m0 + w * 16 + aq * 4 + r;
            if (node < N) {
#pragma unroll
                for (int h = 0; h < 4; ++h) {
                    as_[node * H + h] = ps[h][r];
                    ad_[node * H + h] = pd[h][r];
                }
            }
        }
    }
}

// S2A (unchanged — control).
__global__ __launch_bounds__(256) void s2a_scan(
    const u32* __restrict__ gcnt, u32* __restrict__ gbase, u32* __restrict__ tot)
{
    __shared__ u32 wsum[4];
    const int b = blockIdx.x, t = threadIdx.x, lane = t & 63, w = t >> 6;
    const u32 v = gcnt[b * NCH + t];
    u32 incl = v;
#pragma unroll
    for (int off = 1; off < 64; off <<= 1) {
        u32 u = __shfl_up(incl, off, 64);
        if (lane >= off) incl += u;
    }
    if (lane == 63) wsum[w] = incl;
    __syncthreads();
    u32 wpre = 0;
#pragma unroll
    for (int i = 0; i < 4; ++i) if (i < w) wpre += wsum[i];
    gbase[b * NCH + t] = wpre + incl - v;
    if (t == 255) tot[b] = wpre + incl;
}

// KBINB (unchanged — control).
__global__ __launch_bounds__(256) void kbinB(
    const int* __restrict__ ei, const u32* __restrict__ gbase,
    const u32* __restrict__ tot, u32* __restrict__ pairs)
{
    __shared__ u32 sl[NB];
    __shared__ u32 lfill[NB];
    __shared__ u32 wsum[4];
    const int t = threadIdx.x, lane = t & 63, w = t >> 6;
    const int c = blockIdx.x;

    u32 carry = 0;
    for (int q = 0; q < 4; ++q) {
        const int idx = q * 256 + t;
        const u32 v = (idx < NB) ? tot[idx] : 0u;
        u32 incl = v;
#pragma unroll
        for (int off = 1; off < 64; off <<= 1) {
            u32 u = __shfl_up(incl, off, 64);
            if (lane >= off) incl += u;
        }
        if (lane == 63) wsum[w] = incl;
        __syncthreads();
        u32 wpre = 0, wtot = 0;
#pragma unroll
        for (int i = 0; i < 4; ++i) { const u32 s = wsum[i]; wtot += s; if (i < w) wpre += s; }
        if (idx < NB) sl[idx] = carry + wpre + (incl - v) + gbase[(size_t)idx * NCH + c];
        carry += wtot;
        __syncthreads();
    }
    for (int i = t; i < NB; i += 256) lfill[i] = 0u;
    __syncthreads();

    const int base = c * CHUNK;
    for (int i = t; i < CHUNK; i += 256) {
        const u32 src = (u32)ei[base + i];
        const u32 dst = (u32)ei[E + base + i];
        const u32 b = dst >> 6;
        const u32 pos = atomicAdd(&lfill[b], 1u);
        pairs[sl[b] + pos] = src | ((dst & 63u) << 16);
    }
}

// KFILL2 (unchanged — control).
__global__ __launch_bounds__(256) void kfill2(
    const u32* __restrict__ pairs, const u32* __restrict__ tot,
    int* __restrict__ row_ptr, u16* __restrict__ col)
{
    __shared__ u32 spr[CAP];
    __shared__ u16 scol[CAP];
    __shared__ int jcnt[64], joff[64], jcur[64];
    __shared__ u32 rsum[4];
    const int b = blockIdx.x, t = threadIdx.x;
    const int lane = t & 63, w = t >> 6;

    u32 part = 0;
    for (int i = t; i < b; i += 256) part += tot[i];
#pragma unroll
    for (int off = 32; off; off >>= 1) part += __shfl_xor(part, off, 64);
    if (lane == 0) rsum[w] = part;
    if (t < 64) jcnt[t] = 0;
    __syncthreads();
    const int base = (int)(rsum[0] + rsum[1] + rsum[2] + rsum[3]);
    const int cntb = (int)tot[b];

    const u32* pr = pairs + base;
    for (int i = t; i < cntb; i += 256) spr[i] = pr[i];
    __syncthreads();
    for (int i = t; i < cntb; i += 256) atomicAdd(&jcnt[spr[i] >> 16], 1);
    __syncthreads();
    if (t < 64) {
        int v = jcnt[t], incl = v;
#pragma unroll
        for (int off = 1; off < 64; off <<= 1) {
            int u = __shfl_up(incl, off, 64);
            if (t >= off) incl += u;
        }
        joff[t] = incl - v;
        const int n = b * 64 + t;
        if (n < N) row_ptr[n] = base + joff[t];
        jcur[t] = 0;
    }
    __syncthreads();
    for (int i = t; i < cntb; i += 256) {
        const u32 p = spr[i];
        const int j = p >> 16;
        const int pos = atomicAdd(&jcur[j], 1);
        scol[joff[j] + pos] = (u16)(p & 0xFFFFu);
    }
    __syncthreads();
    for (int i = t; i < cntb; i += 256) col[base + i] = scol[i];
    if (b == 0 && t == 0) row_ptr[N] = E;
}

// KD v4 (unchanged — control), two half-dispatches via n0 offset.
__global__ __launch_bounds__(256) void kd_agg_ln(
    const int* __restrict__ row_ptr, const u16* __restrict__ col,
    const u32* __restrict__ hb, const float* __restrict__ as_,
    const float* __restrict__ ad_,
    const float* __restrict__ bias, const float* __restrict__ gamma,
    const float* __restrict__ beta, float* __restrict__ out, int n0)
{
    __shared__ float wlds[4][64];
    const int tid  = threadIdx.x;
    const int lane = tid & 63;
    const int wv   = __builtin_amdgcn_readfirstlane(tid >> 6);
    const int n    = __builtin_amdgcn_readfirstlane(n0 + (int)blockIdx.x * 4 + (tid >> 6));
    if (n >= N) return;

    const int head  = lane >> 4;
    const int eoff  = lane & 15;
    const int wbase = head << 4;
    float* __restrict__ wrow = wlds[wv];

    const float adn = ad_[n * H + head];
    const float asn = as_[n * H + head];

    float ls = asn + adn;
    ls = fmaxf(ls, NEG * ls);
    const float wself = __expf(ls);
    float den = (eoff == 0) ? wself : 0.f;
    const u32 hvs = hb[n * 64 + lane];
    float num0 = wself * lo16(hvs);
    float num1 = wself * hi16(hvs);

    const int k0  = row_ptr[n];
    const int deg = row_ptr[n + 1] - k0;
    const int ntiles = (deg + 15) >> 4;

    const int cnt0 = deg < 16 ? deg : 16;
    const int cnt1 = (deg - 16) < 16 ? (deg - 16) : 16;
    int colv_cur = (eoff < cnt0) ? (int)col[k0 + eoff]      : 0;
    int colv_nxt = (eoff < cnt1) ? (int)col[k0 + 16 + eoff] : 0;
    float a_cur  = as_[colv_cur * H + head];
    int cntc = cnt0, cntn = cnt1;

    int k = k0;
    for (int t = 0; t < ntiles; ++t, k += 16) {
        const int rem2 = deg - 16 * (t + 2);
        const int cnt2 = rem2 < 16 ? rem2 : 16;
        const int cf_raw = (int)col[k + 32 + eoff];
        const int colv_f = (eoff < cnt2) ? cf_raw : 0;

        float le = a_cur + adn;
        le = fmaxf(le, NEG * le);
        const float w = (eoff < cntc) ? __expf(le) : 0.f;
        den += w;
        wrow[lane] = w;
        const int colc = colv_cur;

#define GL(i) const u32* rp##i = hb + ((size_t)(u32)__builtin_amdgcn_readlane(colc, i) << 6); \
              const u32 v##i = rp##i[lane];
        GL(0) GL(1) GL(2) GL(3) GL(4) GL(5) GL(6) GL(7)
        GL(8) GL(9) GL(10) GL(11) GL(12) GL(13) GL(14) GL(15)
#undef GL
        __builtin_amdgcn_sched_barrier(0);

        const float a_n = as_[colv_nxt * H + head];
        __builtin_amdgcn_sched_barrier(0);

        {
            const float4 wa = *(const float4*)(wrow + wbase + 0);
            num0 = fmaf(wa.x, lo16(v0), num0);  num1 = fmaf(wa.x, hi16(v0), num1);
            num0 = fmaf(wa.y, lo16(v1), num0);  num1 = fmaf(wa.y, hi16(v1), num1);
            num0 = fmaf(wa.z, lo16(v2), num0);  num1 = fmaf(wa.z, hi16(v2), num1);
            num0 = fmaf(wa.w, lo16(v3), num0);  num1 = fmaf(wa.w, hi16(v3), num1);
            const float4 wb = *(const float4*)(wrow + wbase + 4);
            num0 = fmaf(wb.x, lo16(v4), num0);  num1 = fmaf(wb.x, hi16(v4), num1);
            num0 = fmaf(wb.y, lo16(v5), num0);  num1 = fmaf(wb.y, hi16(v5), num1);
            num0 = fmaf(wb.z, lo16(v6), num0);  num1 = fmaf(wb.z, hi16(v6), num1);
            num0 = fmaf(wb.w, lo16(v7), num0);  num1 = fmaf(wb.w, hi16(v7), num1);
            const float4 wc = *(const float4*)(wrow + wbase + 8);
            num0 = fmaf(wc.x, lo16(v8), num0);  num1 = fmaf(wc.x, hi16(v8), num1);
            num0 = fmaf(wc.y, lo16(v9), num0);  num1 = fmaf(wc.y, hi16(v9), num1);
            num0 = fmaf(wc.z, lo16(v10), num0); num1 = fmaf(wc.z, hi16(v10), num1);
            num0 = fmaf(wc.w, lo16(v11), num0); num1 = fmaf(wc.w, hi16(v11), num1);
            const float4 wd = *(const float4*)(wrow + wbase + 12);
            num0 = fmaf(wd.x, lo16(v12), num0); num1 = fmaf(wd.x, hi16(v12), num1);
            num0 = fmaf(wd.y, lo16(v13), num0); num1 = fmaf(wd.y, hi16(v13), num1);
            num0 = fmaf(wd.z, lo16(v14), num0); num1 = fmaf(wd.z, hi16(v14), num1);
            num0 = fmaf(wd.w, lo16(v15), num0); num1 = fmaf(wd.w, hi16(v15), num1);
        }

        colv_cur = colv_nxt; colv_nxt = colv_f;
        a_cur = a_n;
        cntc = cntn; cntn = cnt2;
    }

#pragma unroll
    for (int off = 1; off < 16; off <<= 1) den += __shfl_xor(den, off, 64);

    const int c0 = lane * 2;
    const float inv_den = 1.f / (den + SEPS);
    const float2 bi = *(const float2*)(bias + c0);
    float v0 = num0 * inv_den + bi.x;
    float v1 = num1 * inv_den + bi.y;

    float sum = v0 + v1;
#pragma unroll
    for (int off = 32; off; off >>= 1) sum += __shfl_xor(sum, off, 64);
    const float mu = sum * (1.0f / C);
    const float d0 = v0 - mu, d1 = v1 - mu;
    float sq = d0 * d0 + d1 * d1;
#pragma unroll
    for (int off = 32; off; off >>= 1) sq += __shfl_xor(sq, off, 64);
    const float inv = rsqrtf(sq * (1.0f / C) + LEPS);
    const float2 ga = *(const float2*)(gamma + c0);
    const float2 be = *(const float2*)(beta  + c0);
    float y0 = d0 * inv * ga.x + be.x;
    float y1 = d1 * inv * ga.y + be.y;
    y0 = y0 > 0.f ? y0 : __expf(y0) - 1.f;
    y1 = y1 > 0.f ? y1 : __expf(y1) - 1.f;
    float2 o; o.x = y0; o.y = y1;
    *(float2*)(out + (size_t)n * C + c0) = o;
}

extern "C" void kernel_launch(void* const* d_in, const int* in_sizes, int n_in,
                              void* d_out, int out_size, void* d_ws, size_t ws_size,
                              hipStream_t stream)
{
    const float* x     = (const float*)d_in[0];
    const int*   ei    = (const int*)  d_in[1];
    const float* W     = (const float*)d_in[2];
    const float* att_s = (const float*)d_in[3];
    const float* att_d = (const float*)d_in[4];
    const float* bias  = (const float*)d_in[5];
    const float* gamma = (const float*)d_in[6];
    const float* beta  = (const float*)d_in[7];
    float* out = (float*)d_out;

    // ws (~25.9 MB): hb bf16[N*C] | as_ | ad_ | pairs u32[E] | col u16[E+64]
    //   | row_ptr int[N+1] | gcnt u32[NB*256] | gbase u32[NB*256] | tot u32[NB]
    //   | wt_hi/lo u16[128*128]
    char* p = (char*)d_ws;
    bf16*  hb      = (bf16*)p;   p += (size_t)N * C * sizeof(bf16);
    float* as_     = (float*)p;  p += (size_t)N * H * sizeof(float);
    float* ad_     = (float*)p;  p += (size_t)N * H * sizeof(float);
    u32*   pairs   = (u32*)p;    p += (size_t)E * sizeof(u32);
    u16*   col     = (u16*)p;    p += ((size_t)(E + 64) * sizeof(u16) + 15) & ~(size_t)15;
    int*   row_ptr = (int*)p;    p += ((size_t)(N + 1) * sizeof(int) + 15) & ~(size_t)15;
    u32*   gcnt    = (u32*)p;    p += (size_t)NB * NCH * sizeof(u32);
    u32*   gbase   = (u32*)p;    p += (size_t)NB * NCH * sizeof(u32);
    u32*   tot     = (u32*)p;    p += (((size_t)NB * sizeof(u32)) + 15) & ~(size_t)15;
    u16*   wt_hi   = (u16*)p;    p += (size_t)128 * 128 * sizeof(u16);
    u16*   wt_lo   = (u16*)p;

    k0_wprep<<<64, 256, 0, stream>>>(W, wt_hi, wt_lo);
    f1_gemm_count<<<GEMM_BLOCKS + NCH, 256, 0, stream>>>(
        x, wt_hi, wt_lo, att_s, att_d, ei, (u16*)hb, as_, ad_, gcnt);
    s2a_scan<<<NB, 256, 0, stream>>>(gcnt, gbase, tot);
    kbinB<<<NCH, 256, 0, stream>>>(ei, gbase, tot, pairs);
    kfill2<<<NB, 256, 0, stream>>>(pairs, tot, row_ptr, col);
    kd_agg_ln<<<(25000 * 64) / 256, 256, 0, stream>>>(
        row_ptr, col, (const u32*)hb, as_, ad_, bias, gamma, beta, out, 0);
    kd_agg_ln<<<(25000 * 64) / 256, 256, 0, stream>>>(
        row_ptr, col, (const u32*)hb, as_, ad_, bias, gamma, beta, out, 25000);
}